// Round 2
// baseline (348.856 us; speedup 1.0000x reference)
//
#include <hip/hip_runtime.h>

typedef short short4v __attribute__((ext_vector_type(4)));
typedef short short8v __attribute__((ext_vector_type(8)));
typedef float f32x4 __attribute__((ext_vector_type(4)));

#define MFMA(a, b, c) __builtin_amdgcn_mfma_f32_16x16x32_bf16((a), (b), (c), 0, 0, 0)

__device__ __forceinline__ short f2bf(float f) {
  unsigned u = __float_as_uint(f);
  unsigned r = u + 0x7fffu + ((u >> 16) & 1u);  // round-to-nearest-even
  return (short)(r >> 16);
}

__device__ __forceinline__ short4v f2bf4(float4 v) {
  short4v s;
  s.x = f2bf(v.x); s.y = f2bf(v.y); s.z = f2bf(v.z); s.w = f2bf(v.w);
  return s;
}

__device__ __forceinline__ short8v pack8(float4 a, float4 b) {
  short8v s;
  s[0] = f2bf(a.x); s[1] = f2bf(a.y); s[2] = f2bf(a.z); s[3] = f2bf(a.w);
  s[4] = f2bf(b.x); s[5] = f2bf(b.y); s[6] = f2bf(b.z); s[7] = f2bf(b.w);
  return s;
}

// Direct HBM->LDS, 16B per lane; LDS dest = uniform base + lane*16.
__device__ __forceinline__ void gload_lds16(const void* g, void* l) {
  __builtin_amdgcn_global_load_lds(
      (const __attribute__((address_space(1))) unsigned int*)g,
      (__attribute__((address_space(3))) unsigned int*)l, 16, 0, 0);
}

// Packed-fragment index for B weights: row n = h*64 + nt*16 + col, k = ks*32 + quad*8 + j
// -> packed[h*16384 + (ks*4+nt)*512 + (quad*16+col)*8 + j]
// A wave's B-fragment load is ONE contiguous 1KB global_load_dwordx4.

// prep1: wvo = Wo @ Wv (written directly in packed bf16), bvo = Wo@bv + bo
__global__ __launch_bounds__(256) void prep1_kernel(
    const float* __restrict__ Wv, const float* __restrict__ Wo,
    const float* __restrict__ bv, const float* __restrict__ bo,
    short* __restrict__ pvo, float* __restrict__ bvo) {
  __shared__ float srow[256];
  __shared__ float red[256];
  const int n = blockIdx.x, k = threadIdx.x;
  const float wov = Wo[n * 256 + k];
  srow[k] = wov;
  red[k] = wov * bv[k];
  __syncthreads();
  float acc = 0.f;
#pragma unroll 16
  for (int j = 0; j < 256; ++j) acc += srow[j] * Wv[j * 256 + k];
  const int h = n >> 6, nt = (n >> 4) & 3, col = n & 15;
  const int ks = k >> 5, quad = (k >> 3) & 3, j8 = k & 7;
  pvo[h * 16384 + (ks * 4 + nt) * 512 + (quad * 16 + col) * 8 + j8] = f2bf(acc);
  for (int s = 128; s > 0; s >>= 1) {
    if (k < s) red[k] += red[k + s];
    __syncthreads();
  }
  if (k == 0) bvo[n] = red[0] + bo[n];
}

// prep2: pack Wq/Wk/Wv/Wo into fragment order (bf16). 8192 threads, 16B per store.
__global__ __launch_bounds__(256) void pack_kernel(
    const float* __restrict__ Wq, const float* __restrict__ Wk,
    const float* __restrict__ Wv, const float* __restrict__ Wo,
    short* __restrict__ pq, short* __restrict__ pk,
    short* __restrict__ pv, short* __restrict__ po) {
  const int g = blockIdx.x * 256 + threadIdx.x;  // 0..8191
  const int n = g >> 5;
  const int c8 = g & 31;
  const int h = n >> 6, nt = (n >> 4) & 3, col = n & 15;
  const int ks = c8 >> 2, quad = c8 & 3;
  const int src = n * 256 + c8 * 8;
  const int dst = h * 16384 + (ks * 4 + nt) * 512 + (quad * 16 + col) * 8;
  const float4* q4 = (const float4*)(Wq + src);
  const float4* k4 = (const float4*)(Wk + src);
  const float4* v4 = (const float4*)(Wv + src);
  const float4* o4 = (const float4*)(Wo + src);
  float4 qa = q4[0], qb = q4[1], ka = k4[0], kb = k4[1];
  float4 va = v4[0], vb = v4[1], oa = o4[0], ob = o4[1];
  *(short4v*)(pq + dst) = f2bf4(qa); *(short4v*)(pq + dst + 4) = f2bf4(qb);
  *(short4v*)(pk + dst) = f2bf4(ka); *(short4v*)(pk + dst + 4) = f2bf4(kb);
  *(short4v*)(pv + dst) = f2bf4(va); *(short4v*)(pv + dst + 4) = f2bf4(vb);
  *(short4v*)(po + dst) = f2bf4(oa); *(short4v*)(po + dst + 4) = f2bf4(ob);
}

// Pass A: Q = p@Wq, dK = (c0-c1)@Wk, dV' = (c0-c1)@Wv in one triple-stream pass.
// p from packed bf16 LDS (contiguous per-lane 16B); c0/c1 raw fp32 from the
// DMA-staged, XOR-swizzled LDS tile; d computed fp32 then RNE-cvt per fragment.
__device__ __forceinline__ void passA(const short* bufP, const float* bufC,
                                      const short* __restrict__ wq,
                                      const short* __restrict__ wk,
                                      const short* __restrict__ wv, int lane,
                                      f32x4 accQ[2][4], f32x4 accK[2][4],
                                      f32x4 accV[2][4]) {
  const int rlo = lane & 15, quad = lane >> 4, r7 = lane & 7;
  short8v qb0 = *(const short8v*)(wq);
  short8v qb1 = *(const short8v*)(wq + 512);
  short8v kb0 = *(const short8v*)(wk);
  short8v kb1 = *(const short8v*)(wk + 512);
  short8v vb0 = *(const short8v*)(wv);
  short8v vb1 = *(const short8v*)(wv + 512);
#pragma unroll
  for (int ks = 0; ks < 8; ++ks) {
    short8v pf[2], df[2];
#pragma unroll
    for (int ms = 0; ms < 2; ++ms) {
      pf[ms] = *(const short8v*)(bufP + ((ks * 2 + ms) * 64 + lane) * 8);
      const int row = ms * 16 + rlo;
      const int cb = ks * 8 + quad * 2;
      const float* rb = bufC + (row << 9);
      float4 c0a = *(const float4*)(rb + (((cb) ^ r7) << 2));
      float4 c0b = *(const float4*)(rb + (((cb + 1) ^ r7) << 2));
      float4 c1a = *(const float4*)(rb + (((64 + cb) ^ r7) << 2));
      float4 c1b = *(const float4*)(rb + (((64 + cb + 1) ^ r7) << 2));
      float4 d0 = make_float4(c0a.x - c1a.x, c0a.y - c1a.y, c0a.z - c1a.z, c0a.w - c1a.w);
      float4 d1 = make_float4(c0b.x - c1b.x, c0b.y - c1b.y, c0b.z - c1b.z, c0b.w - c1b.w);
      df[ms] = pack8(d0, d1);
    }
#pragma unroll
    for (int nt = 0; nt < 4; ++nt) {
      const int f = ks * 4 + nt;
      short8v qn = *(const short8v*)(wq + ((f + 2) & 31) * 512);
      short8v kn = *(const short8v*)(wk + ((f + 2) & 31) * 512);
      short8v vn = *(const short8v*)(wv + ((f + 2) & 31) * 512);
      accQ[0][nt] = MFMA(pf[0], qb0, accQ[0][nt]);
      accQ[1][nt] = MFMA(pf[1], qb0, accQ[1][nt]);
      accK[0][nt] = MFMA(df[0], kb0, accK[0][nt]);
      accK[1][nt] = MFMA(df[1], kb0, accK[1][nt]);
      accV[0][nt] = MFMA(df[0], vb0, accV[0][nt]);
      accV[1][nt] = MFMA(df[1], vb0, accV[1][nt]);
      qb0 = qb1; qb1 = qn;
      kb0 = kb1; kb1 = kn;
      vb0 = vb1; vb1 = vn;
    }
  }
}

// Pass B: out = c1@Wvo^T + gdV@Wo^T. c1 fp32+cvt from LDS, gdV packed bf16.
__device__ __forceinline__ void passB(const short* bufG, const float* bufC,
                                      const short* __restrict__ wvo,
                                      const short* __restrict__ wo, int lane,
                                      f32x4 acc1[2][4], f32x4 acc2[2][4]) {
  const int rlo = lane & 15, quad = lane >> 4, r7 = lane & 7;
  short8v v0 = *(const short8v*)(wvo);
  short8v v1 = *(const short8v*)(wvo + 512);
  short8v o0 = *(const short8v*)(wo);
  short8v o1 = *(const short8v*)(wo + 512);
#pragma unroll
  for (int ks = 0; ks < 8; ++ks) {
    short8v cf[2], gf[2];
#pragma unroll
    for (int ms = 0; ms < 2; ++ms) {
      gf[ms] = *(const short8v*)(bufG + ((ks * 2 + ms) * 64 + lane) * 8);
      const int row = ms * 16 + rlo;
      const int cb = ks * 8 + quad * 2;
      const float* rb = bufC + (row << 9);
      float4 c1a = *(const float4*)(rb + (((64 + cb) ^ r7) << 2));
      float4 c1b = *(const float4*)(rb + (((64 + cb + 1) ^ r7) << 2));
      cf[ms] = pack8(c1a, c1b);
    }
#pragma unroll
    for (int nt = 0; nt < 4; ++nt) {
      const int f = ks * 4 + nt;
      short8v vn = *(const short8v*)(wvo + ((f + 2) & 31) * 512);
      short8v on = *(const short8v*)(wo + ((f + 2) & 31) * 512);
      acc1[0][nt] = MFMA(cf[0], v0, acc1[0][nt]);
      acc1[1][nt] = MFMA(cf[1], v0, acc1[1][nt]);
      acc2[0][nt] = MFMA(gf[0], o0, acc2[0][nt]);
      acc2[1][nt] = MFMA(gf[1], o0, acc2[1][nt]);
      v0 = v1; v1 = vn;
      o0 = o1; o1 = on;
    }
  }
}

__global__ __launch_bounds__(256, 2) void fused_kernel(
    const float* __restrict__ pred, const float* __restrict__ cemb,
    const short* __restrict__ pq, const short* __restrict__ pk,
    const short* __restrict__ pv, const short* __restrict__ po,
    const short* __restrict__ pvo, const float* __restrict__ bq,
    const float* __restrict__ bvo, float* __restrict__ out) {
  // 64KB: 32 rows x 512 floats (c0|c1), chunk-XOR-swizzled within each 2KB row
  __shared__ __align__(16) float bufC[32 * 512];
  // 16KB: p as packed bf16 A-fragments [(ks*2+ms)*64 + lane][8]; later gdV
  __shared__ __align__(16) short bufP[8192];
  const int tid = threadIdx.x;
  const size_t t0 = (size_t)blockIdx.x * 32;
  const int lane = tid & 63;
  const int w = tid >> 6;  // wave = head

  // ---- Stage ----
  // 1) p: 8 dwordx4 into registers (issued first so their waitcnt doesn't
  //    drain the DMAs), converted to packed bf16 below.
  const int r = tid >> 3;
  const int c8 = tid & 7;
  const float4* prow = (const float4*)(pred + (t0 + r) * 256);
  float4 pv_[8];
#pragma unroll
  for (int i = 0; i < 8; ++i) pv_[i] = prow[c8 + 8 * i];

  // 2) cemb rows: 16 global_load_lds per wave (raw fp32, no VGPR round-trip,
  //    all in flight). Source lane-XOR pre-swizzled so LDS chunk c holds
  //    global chunk c^(row&7); readers apply the same XOR.
  {
#pragma unroll
    for (int rr = 0; rr < 8; ++rr) {
      const int row = w * 8 + rr;
      const int r7 = row & 7;
      const float* gb = cemb + (t0 + row) * 512;
      float* lb = bufC + row * 512;
      const int lsw = (lane ^ r7) << 2;
      gload_lds16(gb + lsw, lb);
      gload_lds16(gb + 256 + lsw, lb + 256);
    }
  }

  const int col = lane & 15;
  const int quad = lane >> 4;
  const int nbase = w * 64;
  const int woff = w * 16384 + lane * 8;

  float bqv[4], bov[4];
#pragma unroll
  for (int nt = 0; nt < 4; ++nt) bqv[nt] = bq[nbase + nt * 16 + col];
#pragma unroll
  for (int nt = 0; nt < 4; ++nt) bov[nt] = bvo[nbase + nt * 16 + col];

  // 3) p -> packed bf16 LDS tile
  {
    const int ms = r >> 4;
    const int r15 = r & 15;
#pragma unroll
    for (int i = 0; i < 8; ++i) {
      const int k0 = 4 * (c8 + 8 * i);
      const int ks = k0 >> 5, q2 = (k0 >> 3) & 3, j = k0 & 7;
      *(short4v*)(bufP + ((ks * 2 + ms) * 64 + q2 * 16 + r15) * 8 + j) =
          f2bf4(pv_[i]);
    }
  }
  asm volatile("s_waitcnt vmcnt(0)");
  __syncthreads();

  // ---- Pass A: Q, dK, dV (triple B-stream) ----
  f32x4 accQ[2][4] = {};
  f32x4 accK[2][4] = {};
  f32x4 accV[2][4] = {};
  passA(bufP, bufC, pq + woff, pk + woff, pv + woff, lane, accQ, accK, accV);

  // z[m][head] = (Q+bq) . dK over this head's 64 cols; reduce across the
  // 16 lanes of each quad-row; g = sigmoid(z/sqrt(D))
  float g[2][4];
#pragma unroll
  for (int ms = 0; ms < 2; ++ms) {
#pragma unroll
    for (int rr = 0; rr < 4; ++rr) {
      float zz = 0.f;
#pragma unroll
      for (int nt = 0; nt < 4; ++nt)
        zz += (accQ[ms][nt][rr] + bqv[nt]) * accK[ms][nt][rr];
      zz += __shfl_xor(zz, 1);
      zz += __shfl_xor(zz, 2);
      zz += __shfl_xor(zz, 4);
      zz += __shfl_xor(zz, 8);
      g[ms][rr] = 1.f / (1.f + __expf(-0.125f * zz));
    }
  }

  __syncthreads();  // all waves done reading bufP (p-frags)

  // gdV -> bufP as packed bf16 A-tile.
  // Element (row = ms*16+quad*4+rr, k = nbase+nt*16+col):
  //   ks2 = w*2 + (nt>>1), quad2 = ((nt&1)*2 + (col>>3)) & 3, j = col&7
#pragma unroll
  for (int ms = 0; ms < 2; ++ms)
#pragma unroll
    for (int nt = 0; nt < 4; ++nt) {
      const int ks2 = w * 2 + (nt >> 1);
      const int quad2 = ((nt & 1) * 2 + (col >> 3)) & 3;
      const int j = col & 7;
#pragma unroll
      for (int rr = 0; rr < 4; ++rr)
        bufP[((ks2 * 2 + ms) * 64 + quad2 * 16 + quad * 4 + rr) * 8 + j] =
            f2bf(g[ms][rr] * accV[ms][nt][rr]);
    }
  __syncthreads();

  // ---- Pass B: out = c1@Wvo^T + gdV@Wo^T + bvo ----
  f32x4 accO1[2][4] = {};
  f32x4 accO2[2][4] = {};
  passB(bufP, bufC, pvo + woff, po + woff, lane, accO1, accO2);

#pragma unroll
  for (int ms = 0; ms < 2; ++ms)
#pragma unroll
    for (int nt = 0; nt < 4; ++nt)
#pragma unroll
      for (int rr = 0; rr < 4; ++rr)
        out[(t0 + ms * 16 + quad * 4 + rr) * 256 + nbase + nt * 16 + col] =
            accO1[ms][nt][rr] + accO2[ms][nt][rr] + bov[nt];
}

extern "C" void kernel_launch(void* const* d_in, const int* in_sizes, int n_in,
                              void* d_out, int out_size, void* d_ws, size_t ws_size,
                              hipStream_t stream) {
  const float* pred = (const float*)d_in[0];
  const float* cemb = (const float*)d_in[1];
  const float* Wq = (const float*)d_in[2];
  const float* bq = (const float*)d_in[3];
  const float* Wk = (const float*)d_in[4];
  const float* Wv = (const float*)d_in[6];
  const float* bv = (const float*)d_in[7];
  const float* Wo = (const float*)d_in[8];
  const float* bo = (const float*)d_in[9];
  float* out = (float*)d_out;

  short* pq = (short*)d_ws;
  short* pk = pq + 65536;
  short* pv = pk + 65536;
  short* po = pv + 65536;
  short* pvo = po + 65536;
  float* bvo = (float*)(pvo + 65536);  // total ws use: 656,384 bytes

  prep1_kernel<<<256, 256, 0, stream>>>(Wv, Wo, bv, bo, pvo, bvo);
  pack_kernel<<<32, 256, 0, stream>>>(Wq, Wk, Wv, Wo, pq, pk, pv, po);
  fused_kernel<<<2048, 256, 0, stream>>>(pred, cemb, pq, pk, pv, po, pvo, bq, bvo, out);
}